// Round 3
// baseline (2617.056 us; speedup 1.0000x reference)
//
#include <hip/hip_runtime.h>
#include <hip/hip_bf16.h>
#include <stdint.h>

// Problem geometry (fixed by reference)
#define NQ 4096      // 64*8*8 query rows
#define NS 40960     // 32768 (s1) + 8192 (s_src)
#define CDIM 512
#define QT 256       // q rows per block: 4 q-slots x 64 q/wave
#define QW 64        // q cols per wave (2 groups of 32)
#define SC 64        // s rows per chunk (2 halves of 32)
#define NSPLIT 16    // s-dimension splits (grid.y)
#define SPER (NS / NSPLIT)   // 2560
#define NCHUNK (SPER / SC)   // 40
#define NCAND 480    // per-row candidates: 16 splits * 2 s-halves * 15

typedef float f32x16 __attribute__((ext_vector_type(16)));
typedef __bf16 bf16x8 __attribute__((ext_vector_type(8)));
typedef unsigned int u32x4 __attribute__((ext_vector_type(4)));

__device__ __forceinline__ unsigned short f2bf(float f) {
    uint32_t u = __builtin_bit_cast(uint32_t, f);
    u += 0x7fffu + ((u >> 16) & 1u);   // RNE (finite values only here)
    return (unsigned short)(u >> 16);
}

// CK-proven cast pattern: generic -> AS1/AS3 via uintptr
__device__ __forceinline__ void async_load16(const void* g, void* l) {
    auto gp = reinterpret_cast<const __attribute__((address_space(1))) uint32_t*>(
        reinterpret_cast<uintptr_t>(g));
    auto lp = reinterpret_cast<__attribute__((address_space(3))) uint32_t*>(
        reinterpret_cast<uintptr_t>(l));
    __builtin_amdgcn_global_load_lds(gp, lp, 16 /*bytes, literal*/, 0, 0);
}

// Branchless sorted-desc insert: r[i] = med3(v, r[i-1], r[i]) descending, then max.
// 15 VALU ops, no control flow (keeps regalloc clean -> no B-frag demotion).
__device__ __forceinline__ void ins15(float (&r)[15], float v) {
#pragma unroll
    for (int i = 14; i >= 1; --i) r[i] = __builtin_amdgcn_fmed3f(v, r[i - 1], r[i]);
    r[0] = fmaxf(r[0], v);
}

// ---------------- Phase A1: pool q (4x4 mean) + row-normalize -> bf16 ----------------
// XCD-chunked swizzle: the 64 spatial blocks of one b co-locate on one XCD.
__global__ __launch_bounds__(256) void pool_q_norm(const float* __restrict__ q,
                                                   unsigned short* __restrict__ qn) {
    int i0 = blockIdx.x;
    int r = (i0 & 7) * 512 + (i0 >> 3);   // bijective: 4096 = 8 * 512
    int b = r >> 6, h = (r >> 3) & 7, w = r & 7;
    int t = threadIdx.x, lane = t & 63, wid = t >> 6;
    float vals[2];
    float ss = 0.f;
#pragma unroll
    for (int e = 0; e < 2; ++e) {
        int c = 2 * t + e;
        const float* base = q + (((size_t)(b * 512 + c) * 32 + 4 * h) * 32 + 4 * w);
        float s = 0.f;
#pragma unroll
        for (int i = 0; i < 4; ++i) {
            float4 v = *(const float4*)(base + i * 32);
            s += (v.x + v.y) + (v.z + v.w);
        }
        s *= (1.f / 16.f);
        vals[e] = s;
        ss += s * s;
    }
#pragma unroll
    for (int o = 32; o > 0; o >>= 1) ss += __shfl_xor(ss, o, 64);
    __shared__ float red[4];
    if (lane == 0) red[wid] = ss;
    __syncthreads();
    float inv = 1.0f / sqrtf(red[0] + red[1] + red[2] + red[3]);
    ushort2 o2;
    o2.x = f2bf(vals[0] * inv);
    o2.y = f2bf(vals[1] * inv);
    *(ushort2*)(qn + (size_t)r * CDIM + 2 * t) = o2;
}

// ------- Phase A2: pool S at BOTH scales in one pass + row-normalize -> bf16 -------
__global__ __launch_bounds__(256) void pool_s_norm(const float* __restrict__ S,
                                                   unsigned short* __restrict__ sn) {
    int i0 = blockIdx.x;
    int rb = (i0 & 7) * 1024 + (i0 >> 3);   // bijective: 8192 = 8 * 1024
    int b = rb >> 6, h2 = (rb >> 3) & 7, w2 = rb & 7;
    int t = threadIdx.x, lane = t & 63, wid = t >> 6;
    float vals[2][5];
    float ss[5] = {0.f, 0.f, 0.f, 0.f, 0.f};
#pragma unroll
    for (int e = 0; e < 2; ++e) {
        int c = 2 * t + e;
        const float* base = S + (((size_t)(b * 512 + c) * 32 + 4 * h2) * 32 + 4 * w2);
        float4 v0 = *(const float4*)(base);
        float4 v1 = *(const float4*)(base + 32);
        float4 v2 = *(const float4*)(base + 64);
        float4 v3 = *(const float4*)(base + 96);
        float q00 = v0.x + v0.y + v1.x + v1.y;
        float q01 = v0.z + v0.w + v1.z + v1.w;
        float q10 = v2.x + v2.y + v3.x + v3.y;
        float q11 = v2.z + v2.w + v3.z + v3.w;
        vals[e][0] = q00 * 0.25f;
        vals[e][1] = q01 * 0.25f;
        vals[e][2] = q10 * 0.25f;
        vals[e][3] = q11 * 0.25f;
        vals[e][4] = (q00 + q01 + q10 + q11) * (1.f / 16.f);
#pragma unroll
        for (int k = 0; k < 5; ++k) ss[k] += vals[e][k] * vals[e][k];
    }
    __shared__ float red[5][4];
#pragma unroll
    for (int k = 0; k < 5; ++k) {
        float v = ss[k];
#pragma unroll
        for (int o = 32; o > 0; o >>= 1) v += __shfl_xor(v, o, 64);
        if (lane == 0) red[k][wid] = v;
    }
    __syncthreads();
    float inv[5];
#pragma unroll
    for (int k = 0; k < 5; ++k)
        inv[k] = 1.0f / sqrtf(red[k][0] + red[k][1] + red[k][2] + red[k][3]);
    int rows[5];
#pragma unroll
    for (int i = 0; i < 2; ++i)
#pragma unroll
        for (int j = 0; j < 2; ++j)
            rows[i * 2 + j] = b * 256 + (2 * h2 + i) * 16 + (2 * w2 + j);
    rows[4] = 32768 + rb;
#pragma unroll
    for (int k = 0; k < 5; ++k) {
        ushort2 o2;
        o2.x = f2bf(vals[0][k] * inv[k]);
        o2.y = f2bf(vals[1][k] * inv[k]);
        *(ushort2*)(sn + (size_t)rows[k] * CDIM + 2 * t) = o2;
    }
}

// ---------------- Phase B: swapped-operand 32x32x16 MFMA + in-register top-15 ----------------
// grid (16 q-tiles, 16 s-splits) = 256 blocks = 1/CU. 512 threads = 8 waves.
// Wave decomposition: wslot = wid&3 (64 q cols each), shalf = wid>>2 (32 s rows each).
// D[s][q], A = s (LDS, dbuf), B = q (2 groups x 32 frags, 256 VGPR, asm-pinned).
// Each A-read feeds 2 MFMAs (q-group reuse) -> LDS traffic halved vs R2.
// C layout (m74/m101): col = lane&31 = q; each lane owns 2 q-rows, 16 s-vals each.
__global__ __launch_bounds__(512, 1) void sim_topk(const unsigned short* __restrict__ qn,
                                                   const unsigned short* __restrict__ sn,
                                                   float* __restrict__ partial) {
    __shared__ unsigned short Bs[2][SC * CDIM];   // 2 x 64KB, XOR-swizzled rows
    int tid = threadIdx.x, lane = tid & 63, wid = tid >> 6;
    int wslot = wid & 3, shalf = wid >> 2;
    int qbase = blockIdx.x * QT + wslot * QW;
    int sbase = blockIdx.y * SPER;
    char* BsB = (char*)&Bs[0][0];
    const char* snB = (const char*)sn;

    // B fragments (q side): 2 groups x 32 q rows, full K=512. k = ks*16 + (lane>>5)*8 + e.
    u32x4 b[2][32];
#pragma unroll
    for (int g = 0; g < 2; ++g) {
        int qrow = qbase + g * 32 + (lane & 31);
        const unsigned short* qp = qn + (size_t)qrow * CDIM + ((lane >> 5) * 8);
#pragma unroll
        for (int ks = 0; ks < 32; ++ks)
            b[g][ks] = *(const u32x4*)(qp + ks * 16);
    }

    float r0[15], r1[15];
#pragma unroll
    for (int i = 0; i < 15; ++i) { r0[i] = -2.0f; r1[i] = -2.0f; }

    auto stage = [&](int ch, int buf) {
#pragma unroll
        for (int i = 0; i < 8; ++i) {
            int row = i * 8 + wid;                       // wave-uniform
            size_t srcoff = ((size_t)(sbase + ch * SC + row) << 10)
                          + (size_t)((lane * 16) ^ ((row & 7) << 4));
            async_load16(snB + srcoff, BsB + buf * 65536 + row * 1024);
        }
    };

    // A-frag addressing: row = shalf*32 + (lane&31); k-bytes = ks*32 + (lane>>5)*16
    int rlo = lane & 31;
    int swz = (rlo & 7) << 4;
    int rowbase = (shalf * 32 + rlo) * 1024;
    int innerbase = (lane >> 5) * 16;

    stage(0, 0);
    for (int ch = 0; ch < NCHUNK; ++ch) {
        int nxt = (ch + 1) % NCHUNK;          // wrap: last iter re-stages chunk 0 (harmless)
        stage(nxt, (ch + 1) & 1);
        asm volatile("s_waitcnt vmcnt(8)" ::: "memory");   // my 8 loads for chunk ch landed
        __builtin_amdgcn_s_barrier();                      // everyone's landed
        const char* B0 = BsB + (ch & 1) * 65536;
        // Pin B-frags: zero-cost, forces them VGPR-resident (defeats remat-to-global)
#pragma unroll
        for (int g = 0; g < 2; ++g)
#pragma unroll
            for (int ks = 0; ks < 32; ++ks) asm volatile("" : "+v"(b[g][ks]));
        f32x16 acc0 = {0.f}, acc1 = {0.f};
        __builtin_amdgcn_s_setprio(1);
#pragma unroll
        for (int ks = 0; ks < 32; ++ks) {
            int inner = (ks * 32 + innerbase) ^ swz;
            bf16x8 a = __builtin_bit_cast(bf16x8, *(const u32x4*)(B0 + rowbase + inner));
            acc0 = __builtin_amdgcn_mfma_f32_32x32x16_bf16(a, __builtin_bit_cast(bf16x8, b[0][ks]), acc0, 0, 0, 0);
            acc1 = __builtin_amdgcn_mfma_f32_32x32x16_bf16(a, __builtin_bit_cast(bf16x8, b[1][ks]), acc1, 0, 0, 0);
        }
        __builtin_amdgcn_s_setprio(0);
        __builtin_amdgcn_s_barrier();   // all ds_reads of this buffer retired -> stageable

        // Branchless med3 top-15 (15 ops/value, no CF)
#pragma unroll
        for (int e = 0; e < 16; ++e) {
            ins15(r0, acc0[e]);
            ins15(r1, acc1[e]);
        }
    }

    // Emit: partial[qrow][split][shalf][15]
    int q0 = qbase + rlo;
    float* dst0 = partial + (((size_t)q0 * NSPLIT + blockIdx.y) * 2 + shalf) * 15;
    float* dst1 = partial + (((size_t)(q0 + 32) * NSPLIT + blockIdx.y) * 2 + shalf) * 15;
#pragma unroll
    for (int i = 0; i < 15; ++i) { dst0[i] = r0[i]; dst1[i] = r1[i]; }
}

// ---------------- Final: merge 480 candidates/row -> top15 -> LSE/top4 loss ----------------
__global__ __launch_bounds__(64) void topk_loss(const float* __restrict__ partial,
                                                float* __restrict__ accum) {
    int r = blockIdx.x, t = threadIdx.x;
    __shared__ float sc[512];
    __shared__ float top[15];
#pragma unroll
    for (int i = 0; i < 8; ++i) {
        int idx = t + 64 * i;
        sc[idx] = (idx < NCAND) ? partial[(size_t)r * NCAND + idx] : -1e30f;
    }
    __syncthreads();
    for (int round = 0; round < 15; ++round) {
        float m = -1e30f;
        int mi = 0;
#pragma unroll
        for (int i = 0; i < 8; ++i) {
            float v = sc[t + 64 * i];
            if (v > m) { m = v; mi = t + 64 * i; }
        }
#pragma unroll
        for (int o = 32; o > 0; o >>= 1) {
            float om = __shfl_down(m, o, 64);
            int oi = __shfl_down(mi, o, 64);
            if (om > m) { m = om; mi = oi; }
        }
        if (t == 0) { top[round] = m; sc[mi] = -1e30f; }
        __syncthreads();
    }
    if (t == 0) {
        float m = top[0], s = 0.f;
#pragma unroll
        for (int i = 0; i < 15; ++i) s += expf(top[i] - m);
        float lse = m + logf(s);
        float loss = lse - 0.25f * (top[0] + top[1] + top[2] + top[3]);
        atomicAdd(accum, loss);
    }
}

__global__ void finalize_out(const float* __restrict__ accum, float* __restrict__ out) {
    out[0] = accum[0] * (1.0f / (float)NQ);
}

// ---------------- Launch ----------------
extern "C" void kernel_launch(void* const* d_in, const int* in_sizes, int n_in,
                              void* d_out, int out_size, void* d_ws, size_t ws_size,
                              hipStream_t stream) {
    (void)in_sizes; (void)n_in; (void)out_size; (void)ws_size;
    const float* q = (const float*)d_in[0];
    const float* S = (const float*)d_in[1];
    char* ws = (char*)d_ws;
    unsigned short* qn = (unsigned short*)ws;                        // 4,194,304 B
    unsigned short* sn = (unsigned short*)(ws + 4194304);            // 41,943,040 B
    float* partial = (float*)(ws + 4194304 + 41943040);              // 7,864,320 B
    float* accum   = (float*)(ws + 4194304 + 41943040 + 7864320);    // 4 B

    hipMemsetAsync(accum, 0, 4, stream);
    pool_q_norm<<<NQ, 256, 0, stream>>>(q, qn);
    pool_s_norm<<<8192, 256, 0, stream>>>(S, sn);
    dim3 gb(NQ / QT, NSPLIT);
    sim_topk<<<gb, 512, 0, stream>>>(qn, sn, partial);
    topk_loss<<<NQ, 64, 0, stream>>>(partial, accum);
    finalize_out<<<1, 1, 0, stream>>>(accum, (float*)d_out);
}

// Round 4
// 515.773 us; speedup vs baseline: 5.0740x; 5.0740x over previous
//
#include <hip/hip_runtime.h>
#include <hip/hip_bf16.h>
#include <stdint.h>

// Problem geometry (fixed by reference)
#define NQ 4096      // 64*8*8 query rows
#define NS 40960     // 32768 (s1) + 8192 (s_src)
#define CDIM 512
#define QT 256       // q rows per block: 8 waves x 32 q
#define SC 64        // s rows per chunk
#define NSPLIT 16    // s-dimension splits (grid.y)
#define SPER (NS / NSPLIT)   // 2560
#define NCHUNK (SPER / SC)   // 40
#define NCAND 960    // per-row candidates: 16 splits * 2 lane-halves * 2 lists * 15

typedef float f32x16 __attribute__((ext_vector_type(16)));
typedef __bf16 bf16x8 __attribute__((ext_vector_type(8)));
typedef unsigned int u32x4 __attribute__((ext_vector_type(4)));

__device__ __forceinline__ unsigned short f2bf(float f) {
    uint32_t u = __builtin_bit_cast(uint32_t, f);
    u += 0x7fffu + ((u >> 16) & 1u);   // RNE (finite values only here)
    return (unsigned short)(u >> 16);
}
__device__ __forceinline__ float bf2f(unsigned short u) {
    uint32_t x = ((uint32_t)u) << 16;
    return __builtin_bit_cast(float, x);
}

// CK-proven cast pattern: generic -> AS1/AS3 via uintptr
__device__ __forceinline__ void async_load16(const void* g, void* l) {
    auto gp = reinterpret_cast<const __attribute__((address_space(1))) uint32_t*>(
        reinterpret_cast<uintptr_t>(g));
    auto lp = reinterpret_cast<__attribute__((address_space(3))) uint32_t*>(
        reinterpret_cast<uintptr_t>(l));
    __builtin_amdgcn_global_load_lds(gp, lp, 16 /*bytes, literal*/, 0, 0);
}

// Branchless sorted-desc insert: r[i] = med3(v, r[i-1], r[i]) for i=14..1, then max.
__device__ __forceinline__ void ins15(float (&r)[15], float v) {
#pragma unroll
    for (int i = 14; i >= 1; --i) r[i] = __builtin_amdgcn_fmed3f(v, r[i - 1], r[i]);
    r[0] = fmaxf(r[0], v);
}

// ---------------- Phase A1: pool q (4x4 mean) + row-normalize -> bf16 ----------------
// block = (image b, pool-row h): threads read 2 channels x 4 FULL 128B rows each ->
// every fetched line fully used (compulsory traffic only). grid 64*8=512.
__global__ __launch_bounds__(256) void pool_q_norm(const float* __restrict__ q,
                                                   unsigned short* __restrict__ qn) {
    int bb = blockIdx.x >> 3, h = blockIdx.x & 7;
    int t = threadIdx.x, lane = t & 63, wid = t >> 6;
    float vals[2][8];
    float ss[8] = {0, 0, 0, 0, 0, 0, 0, 0};
#pragma unroll
    for (int e = 0; e < 2; ++e) {
        int c = 2 * t + e;
        const float* base = q + ((size_t)(bb * 512 + c) * 1024 + 4 * h * 32);
#pragma unroll
        for (int w2 = 0; w2 < 8; ++w2) vals[e][w2] = 0.f;
#pragma unroll
        for (int i = 0; i < 4; ++i) {
            const float4* row = (const float4*)(base + i * 32);
#pragma unroll
            for (int w2 = 0; w2 < 8; ++w2) {
                float4 v = row[w2];
                vals[e][w2] += (v.x + v.y) + (v.z + v.w);
            }
        }
#pragma unroll
        for (int w2 = 0; w2 < 8; ++w2) {
            vals[e][w2] *= (1.f / 16.f);
            ss[w2] += vals[e][w2] * vals[e][w2];
        }
    }
    __shared__ float red[8][4];
#pragma unroll
    for (int k = 0; k < 8; ++k) {
        float v = ss[k];
#pragma unroll
        for (int o = 32; o > 0; o >>= 1) v += __shfl_xor(v, o, 64);
        if (lane == 0) red[k][wid] = v;
    }
    __syncthreads();
#pragma unroll
    for (int w2 = 0; w2 < 8; ++w2) {
        float inv = rsqrtf(red[w2][0] + red[w2][1] + red[w2][2] + red[w2][3]);
        ushort2 o2;
        o2.x = f2bf(vals[0][w2] * inv);
        o2.y = f2bf(vals[1][w2] * inv);
        *(ushort2*)(qn + (size_t)(bb * 64 + h * 8 + w2) * CDIM + 2 * t) = o2;
    }
}

// ------- Phase A2: pool S at BOTH scales + row-normalize -> bf16 -------
// block = (image b, src-row h2): threads read 2 channels x 4 full rows. The 40
// produced rows (32 s1 + 8 src) are staged raw-bf16 in an LDS tile [40][512],
// norms computed from the tile, then scaled + stored coalesced. grid 128*8=1024.
__global__ __launch_bounds__(256) void pool_s_norm(const float* __restrict__ S,
                                                   unsigned short* __restrict__ sn) {
    int bb = blockIdx.x >> 3, h2 = blockIdx.x & 7;
    int t = threadIdx.x;
    __shared__ unsigned short tile[40 * 512];   // 40KB raw-bf16 values
    __shared__ float rowsum[40];
#pragma unroll
    for (int e = 0; e < 2; ++e) {
        int c = 2 * t + e;
        const float* base = S + ((size_t)(bb * 512 + c) * 1024 + 4 * h2 * 32);
        float s1v[2][16];
#pragma unroll
        for (int j = 0; j < 2; ++j) {
            const float4* r0 = (const float4*)(base + (2 * j) * 32);
            const float4* r1 = (const float4*)(base + (2 * j + 1) * 32);
#pragma unroll
            for (int f = 0; f < 8; ++f) {
                float4 a = r0[f], b2 = r1[f];
                s1v[j][2 * f]     = (a.x + a.y + b2.x + b2.y) * 0.25f;
                s1v[j][2 * f + 1] = (a.z + a.w + b2.z + b2.w) * 0.25f;
            }
        }
#pragma unroll
        for (int j = 0; j < 2; ++j)
#pragma unroll
            for (int w1 = 0; w1 < 16; ++w1)
                tile[(j * 16 + w1) * 512 + c] = f2bf(s1v[j][w1]);
#pragma unroll
        for (int w2 = 0; w2 < 8; ++w2) {
            float src = (s1v[0][2 * w2] + s1v[0][2 * w2 + 1] +
                         s1v[1][2 * w2] + s1v[1][2 * w2 + 1]) * 0.25f;
            tile[(32 + w2) * 512 + c] = f2bf(src);
        }
    }
    __syncthreads();
    // Row sums-of-squares from the tile: 4 threads/row x 128 channels each.
    if (t < 160) {
        int r = t >> 2, p = t & 3;
        const unsigned short* row = &tile[r * 512 + p * 128];
        float s = 0.f;
#pragma unroll
        for (int j = 0; j < 128; ++j) {
            float x = bf2f(row[j]);
            s += x * x;
        }
        s += __shfl_xor(s, 1, 64);
        s += __shfl_xor(s, 2, 64);
        if (p == 0) rowsum[r] = s;
    }
    __syncthreads();
    // Scale + coalesced store: 40 rows x 128 8B-segments = 5120 stores.
#pragma unroll
    for (int k = 0; k < 20; ++k) {
        int idx = t + 256 * k;
        int r = idx >> 7, seg = idx & 127;
        float inv = rsqrtf(rowsum[r]);
        const unsigned short* src = &tile[r * 512 + seg * 4];
        ushort4 o;
        o.x = f2bf(bf2f(src[0]) * inv);
        o.y = f2bf(bf2f(src[1]) * inv);
        o.z = f2bf(bf2f(src[2]) * inv);
        o.w = f2bf(bf2f(src[3]) * inv);
        int grow = (r < 32) ? (bb * 256 + (2 * h2 + (r >> 4)) * 16 + (r & 15))
                            : (32768 + bb * 64 + h2 * 8 + (r - 32));
        *(ushort4*)(sn + (size_t)grow * CDIM + seg * 4) = o;
    }
}

// ---------------- Phase B: swapped-operand 32x32x16 MFMA + in-register top-15 ----------------
// grid (16 q-tiles, 16 s-splits) = 256 blocks = 1/CU. 512 threads = 8 waves.
// Wave owns 32 q-cols (b[32] = 128 VGPR, resident under (512,1) => 256-cap).
// D[s][q]: col=lane&31=q, lane>>5 picks s-row-half. Per lane: 2 interleaved top-15
// lists (halved dep chain); scan of chunk k-1 overlaps MFMA of chunk k (accA/accB).
__global__ __launch_bounds__(512, 1) void sim_topk(const unsigned short* __restrict__ qn,
                                                   const unsigned short* __restrict__ sn,
                                                   float* __restrict__ partial) {
    __shared__ unsigned short Bs[2][SC * CDIM];   // 2 x 64KB, XOR-swizzled rows
    int tid = threadIdx.x, lane = tid & 63, wid = tid >> 6;
    int rlo = lane & 31;
    int qbase = blockIdx.x * QT + wid * 32;
    int sbase = blockIdx.y * SPER;
    char* BsB = (char*)&Bs[0][0];
    const char* snB = (const char*)sn;

    // B fragments (q side): 32 q rows, full K=512. k = ks*16 + (lane>>5)*8 + e.
    u32x4 b[32];
    {
        const unsigned short* qp = qn + (size_t)(qbase + rlo) * CDIM + ((lane >> 5) * 8);
#pragma unroll
        for (int ks = 0; ks < 32; ++ks) b[ks] = *(const u32x4*)(qp + ks * 16);
    }

    float rA[15], rB[15];
#pragma unroll
    for (int i = 0; i < 15; ++i) { rA[i] = -2.0f; rB[i] = -2.0f; }
    f32x16 accA0, accA1, accB0, accB1;
#pragma unroll
    for (int e = 0; e < 16; ++e) { accB0[e] = -2.0f; accB1[e] = -2.0f; }

    auto stage = [&](int ch, int buf) {
#pragma unroll
        for (int i = 0; i < 8; ++i) {
            int row = i * 8 + wid;                       // wave-uniform
            size_t srcoff = ((size_t)(sbase + ch * SC + row) << 10)
                          + (size_t)((lane * 16) ^ ((row & 7) << 4));
            async_load16(snB + srcoff, BsB + buf * 65536 + row * 1024);
        }
    };

    int swz = (rlo & 7) << 4;
    int base0 = rlo * 1024, base1 = (32 + rlo) * 1024;
    int innerbase = (lane >> 5) * 16;

    stage(0, 0);
    stage(1, 1);
    for (int it = 0; it < NCHUNK / 2; ++it) {
        int ch = 2 * it;
        // ---- even chunk (buf0): MFMA -> accA; scan accB (chunk ch-1) ----
        asm volatile("s_waitcnt vmcnt(8)" ::: "memory");   // my stage(ch) landed
        __builtin_amdgcn_s_barrier();                      // everyone's landed
#pragma unroll
        for (int ks = 0; ks < 32; ++ks) asm volatile("" : "+v"(b[ks]));
#pragma unroll
        for (int e = 0; e < 16; ++e) { accA0[e] = 0.f; accA1[e] = 0.f; }
#pragma unroll
        for (int ks = 0; ks < 32; ++ks) {
            int inner = (ks * 32 + innerbase) ^ swz;
            bf16x8 a0 = __builtin_bit_cast(bf16x8, *(const u32x4*)(BsB + base0 + inner));
            bf16x8 a1 = __builtin_bit_cast(bf16x8, *(const u32x4*)(BsB + base1 + inner));
            accA0 = __builtin_amdgcn_mfma_f32_32x32x16_bf16(a0, __builtin_bit_cast(bf16x8, b[ks]), accA0, 0, 0, 0);
            accA1 = __builtin_amdgcn_mfma_f32_32x32x16_bf16(a1, __builtin_bit_cast(bf16x8, b[ks]), accA1, 0, 0, 0);
        }
        // scan previous odd chunk's acc (independent of the MFMAs above -> overlaps)
#pragma unroll
        for (int e = 0; e < 16; ++e) ins15((e & 1) ? rB : rA, accB0[e]);
#pragma unroll
        for (int e = 0; e < 16; ++e) ins15((e & 1) ? rB : rA, accB1[e]);
        __builtin_amdgcn_s_barrier();   // all reads of buf0 retired
        { int n = ch + 2; if (n >= NCHUNK) n -= NCHUNK; stage(n, 0); }

        // ---- odd chunk (buf1): MFMA -> accB; scan accA (chunk ch) ----
        asm volatile("s_waitcnt vmcnt(8)" ::: "memory");
        __builtin_amdgcn_s_barrier();
#pragma unroll
        for (int e = 0; e < 16; ++e) { accB0[e] = 0.f; accB1[e] = 0.f; }
#pragma unroll
        for (int ks = 0; ks < 32; ++ks) {
            int inner = (ks * 32 + innerbase) ^ swz;
            bf16x8 a0 = __builtin_bit_cast(bf16x8, *(const u32x4*)(BsB + 65536 + base0 + inner));
            bf16x8 a1 = __builtin_bit_cast(bf16x8, *(const u32x4*)(BsB + 65536 + base1 + inner));
            accB0 = __builtin_amdgcn_mfma_f32_32x32x16_bf16(a0, __builtin_bit_cast(bf16x8, b[ks]), accB0, 0, 0, 0);
            accB1 = __builtin_amdgcn_mfma_f32_32x32x16_bf16(a1, __builtin_bit_cast(bf16x8, b[ks]), accB1, 0, 0, 0);
        }
#pragma unroll
        for (int e = 0; e < 16; ++e) ins15((e & 1) ? rB : rA, accA0[e]);
#pragma unroll
        for (int e = 0; e < 16; ++e) ins15((e & 1) ? rB : rA, accA1[e]);
        __builtin_amdgcn_s_barrier();
        { int n = ch + 3; if (n >= NCHUNK) n -= NCHUNK; stage(n, 1); }
    }
    // epilogue: scan last odd chunk (39)
#pragma unroll
    for (int e = 0; e < 16; ++e) ins15((e & 1) ? rB : rA, accB0[e]);
#pragma unroll
    for (int e = 0; e < 16; ++e) ins15((e & 1) ? rB : rA, accB1[e]);

    // Emit: partial[qrow][split][sub][15], sub = (lane>>5)*2 + list
    int qrow = qbase + rlo;
    float* dst = partial + (((size_t)qrow * NSPLIT + blockIdx.y) * 4 + (lane >> 5) * 2) * 15;
#pragma unroll
    for (int i = 0; i < 15; ++i) { dst[i] = rA[i]; dst[15 + i] = rB[i]; }
}

// ---------------- Final: merge 960 candidates/row -> top15 -> LSE/top4 loss ----------------
__global__ __launch_bounds__(64) void topk_loss(const float* __restrict__ partial,
                                                float* __restrict__ accum) {
    int r = blockIdx.x, t = threadIdx.x;
    __shared__ float sc[960];
    __shared__ float top[15];
#pragma unroll
    for (int i = 0; i < 15; ++i) sc[t + 64 * i] = partial[(size_t)r * NCAND + t + 64 * i];
    __syncthreads();
    for (int round = 0; round < 15; ++round) {
        float m = -1e30f;
        int mi = 0;
#pragma unroll
        for (int i = 0; i < 15; ++i) {
            float v = sc[t + 64 * i];
            if (v > m) { m = v; mi = t + 64 * i; }
        }
#pragma unroll
        for (int o = 32; o > 0; o >>= 1) {
            float om = __shfl_down(m, o, 64);
            int oi = __shfl_down(mi, o, 64);
            if (om > m) { m = om; mi = oi; }
        }
        if (t == 0) { top[round] = m; sc[mi] = -1e30f; }
        __syncthreads();
    }
    if (t == 0) {
        float m = top[0], s = 0.f;
#pragma unroll
        for (int i = 0; i < 15; ++i) s += expf(top[i] - m);
        float lse = m + logf(s);
        float loss = lse - 0.25f * (top[0] + top[1] + top[2] + top[3]);
        atomicAdd(accum, loss);
    }
}

__global__ void finalize_out(const float* __restrict__ accum, float* __restrict__ out) {
    out[0] = accum[0] * (1.0f / (float)NQ);
}

// ---------------- Launch ----------------
extern "C" void kernel_launch(void* const* d_in, const int* in_sizes, int n_in,
                              void* d_out, int out_size, void* d_ws, size_t ws_size,
                              hipStream_t stream) {
    (void)in_sizes; (void)n_in; (void)out_size; (void)ws_size;
    const float* q = (const float*)d_in[0];
    const float* S = (const float*)d_in[1];
    char* ws = (char*)d_ws;
    unsigned short* qn = (unsigned short*)ws;                        // 4,194,304 B
    unsigned short* sn = (unsigned short*)(ws + 4194304);            // 41,943,040 B
    float* partial = (float*)(ws + 4194304 + 41943040);              // 15,728,640 B
    float* accum   = (float*)(ws + 4194304 + 41943040 + 15728640);   // 4 B

    hipMemsetAsync(accum, 0, 4, stream);
    pool_q_norm<<<512, 256, 0, stream>>>(q, qn);
    pool_s_norm<<<1024, 256, 0, stream>>>(S, sn);
    dim3 gb(NQ / QT, NSPLIT);
    sim_topk<<<gb, 512, 0, stream>>>(qn, sn, partial);
    topk_loss<<<NQ, 64, 0, stream>>>(partial, accum);
    finalize_out<<<1, 1, 0, stream>>>(accum, (float*)d_out);
}

// Round 5
// 395.894 us; speedup vs baseline: 6.6105x; 1.3028x over previous
//
#include <hip/hip_runtime.h>
#include <hip/hip_bf16.h>
#include <stdint.h>

// Problem geometry (fixed by reference)
#define NQ 4096      // 64*8*8 query rows
#define NS 40960     // 32768 (s1) + 8192 (s_src)
#define CDIM 512
#define QT 128       // q rows per block: 4 waves x 32 q
#define SC 32        // s rows per chunk
#define NSPLIT 16    // s-dimension splits
#define SPER (NS / NSPLIT)   // 2560
#define NCHUNK (SPER / SC)   // 80
#define NCAND 480    // per-row candidates: 16 splits * 2 lane-halves * 15

typedef float f32x16 __attribute__((ext_vector_type(16)));
typedef __bf16 bf16x8 __attribute__((ext_vector_type(8)));
typedef unsigned int u32x4 __attribute__((ext_vector_type(4)));

__device__ __forceinline__ unsigned short f2bf(float f) {
    uint32_t u = __builtin_bit_cast(uint32_t, f);
    u += 0x7fffu + ((u >> 16) & 1u);   // RNE (finite values only here)
    return (unsigned short)(u >> 16);
}
__device__ __forceinline__ float bf2f(unsigned short u) {
    uint32_t x = ((uint32_t)u) << 16;
    return __builtin_bit_cast(float, x);
}

// CK-proven cast pattern: generic -> AS1/AS3 via uintptr
__device__ __forceinline__ void async_load16(const void* g, void* l) {
    auto gp = reinterpret_cast<const __attribute__((address_space(1))) uint32_t*>(
        reinterpret_cast<uintptr_t>(g));
    auto lp = reinterpret_cast<__attribute__((address_space(3))) uint32_t*>(
        reinterpret_cast<uintptr_t>(l));
    __builtin_amdgcn_global_load_lds(gp, lp, 16 /*bytes, literal*/, 0, 0);
}

// Branchless sorted-desc insert: r[i] = med3(v, r[i-1], r[i]) for i=14..1, then max.
// Inserting v <= r[14] is a provable no-op, so a wave-uniform __any guard is exact.
__device__ __forceinline__ void ins15(float (&r)[15], float v) {
#pragma unroll
    for (int i = 14; i >= 1; --i) r[i] = __builtin_amdgcn_fmed3f(v, r[i - 1], r[i]);
    r[0] = fmaxf(r[0], v);
}

// ---------------- Phase A1: pool q (4x4 mean) + row-normalize -> bf16 ----------------
// block = (image b, pool-row h): threads read 2 channels x 4 FULL 128B rows each ->
// every fetched line fully used (compulsory traffic only). grid 64*8=512.
__global__ __launch_bounds__(256) void pool_q_norm(const float* __restrict__ q,
                                                   unsigned short* __restrict__ qn) {
    int bb = blockIdx.x >> 3, h = blockIdx.x & 7;
    int t = threadIdx.x, lane = t & 63, wid = t >> 6;
    float vals[2][8];
    float ss[8] = {0, 0, 0, 0, 0, 0, 0, 0};
#pragma unroll
    for (int e = 0; e < 2; ++e) {
        int c = 2 * t + e;
        const float* base = q + ((size_t)(bb * 512 + c) * 1024 + 4 * h * 32);
#pragma unroll
        for (int w2 = 0; w2 < 8; ++w2) vals[e][w2] = 0.f;
#pragma unroll
        for (int i = 0; i < 4; ++i) {
            const float4* row = (const float4*)(base + i * 32);
#pragma unroll
            for (int w2 = 0; w2 < 8; ++w2) {
                float4 v = row[w2];
                vals[e][w2] += (v.x + v.y) + (v.z + v.w);
            }
        }
#pragma unroll
        for (int w2 = 0; w2 < 8; ++w2) {
            vals[e][w2] *= (1.f / 16.f);
            ss[w2] += vals[e][w2] * vals[e][w2];
        }
    }
    __shared__ float red[8][4];
#pragma unroll
    for (int k = 0; k < 8; ++k) {
        float v = ss[k];
#pragma unroll
        for (int o = 32; o > 0; o >>= 1) v += __shfl_xor(v, o, 64);
        if (lane == 0) red[k][wid] = v;
    }
    __syncthreads();
#pragma unroll
    for (int w2 = 0; w2 < 8; ++w2) {
        float inv = rsqrtf(red[w2][0] + red[w2][1] + red[w2][2] + red[w2][3]);
        ushort2 o2;
        o2.x = f2bf(vals[0][w2] * inv);
        o2.y = f2bf(vals[1][w2] * inv);
        *(ushort2*)(qn + (size_t)(bb * 64 + h * 8 + w2) * CDIM + 2 * t) = o2;
    }
}

// ------- Phase A2: pool S at BOTH scales + row-normalize -> bf16 -------
__global__ __launch_bounds__(256) void pool_s_norm(const float* __restrict__ S,
                                                   unsigned short* __restrict__ sn) {
    int bb = blockIdx.x >> 3, h2 = blockIdx.x & 7;
    int t = threadIdx.x;
    __shared__ unsigned short tile[40 * 512];   // 40KB raw-bf16 values
    __shared__ float rowsum[40];
#pragma unroll
    for (int e = 0; e < 2; ++e) {
        int c = 2 * t + e;
        const float* base = S + ((size_t)(bb * 512 + c) * 1024 + 4 * h2 * 32);
        float s1v[2][16];
#pragma unroll
        for (int j = 0; j < 2; ++j) {
            const float4* r0 = (const float4*)(base + (2 * j) * 32);
            const float4* r1 = (const float4*)(base + (2 * j + 1) * 32);
#pragma unroll
            for (int f = 0; f < 8; ++f) {
                float4 a = r0[f], b2 = r1[f];
                s1v[j][2 * f]     = (a.x + a.y + b2.x + b2.y) * 0.25f;
                s1v[j][2 * f + 1] = (a.z + a.w + b2.z + b2.w) * 0.25f;
            }
        }
#pragma unroll
        for (int j = 0; j < 2; ++j)
#pragma unroll
            for (int w1 = 0; w1 < 16; ++w1)
                tile[(j * 16 + w1) * 512 + c] = f2bf(s1v[j][w1]);
#pragma unroll
        for (int w2 = 0; w2 < 8; ++w2) {
            float src = (s1v[0][2 * w2] + s1v[0][2 * w2 + 1] +
                         s1v[1][2 * w2] + s1v[1][2 * w2 + 1]) * 0.25f;
            tile[(32 + w2) * 512 + c] = f2bf(src);
        }
    }
    __syncthreads();
    if (t < 160) {
        int r = t >> 2, p = t & 3;
        const unsigned short* row = &tile[r * 512 + p * 128];
        float s = 0.f;
#pragma unroll
        for (int j = 0; j < 128; ++j) {
            float x = bf2f(row[j]);
            s += x * x;
        }
        s += __shfl_xor(s, 1, 64);
        s += __shfl_xor(s, 2, 64);
        if (p == 0) rowsum[r] = s;
    }
    __syncthreads();
#pragma unroll
    for (int k = 0; k < 20; ++k) {
        int idx = t + 256 * k;
        int r = idx >> 7, seg = idx & 127;
        float inv = rsqrtf(rowsum[r]);
        const unsigned short* src = &tile[r * 512 + seg * 4];
        ushort4 o;
        o.x = f2bf(bf2f(src[0]) * inv);
        o.y = f2bf(bf2f(src[1]) * inv);
        o.z = f2bf(bf2f(src[2]) * inv);
        o.w = f2bf(bf2f(src[3]) * inv);
        int grow = (r < 32) ? (bb * 256 + (2 * h2 + (r >> 4)) * 16 + (r & 15))
                            : (32768 + bb * 64 + h2 * 8 + (r - 32));
        *(ushort4*)(sn + (size_t)grow * CDIM + seg * 4) = o;
    }
}

// ---------------- Phase B: swapped-operand 32x32x16 MFMA + in-register top-15 ----------------
// 512 blocks x 256 threads (4 waves x 32 q = 128-q tile), 2 blocks/CU.
// XCD-pinned decode: all 32 x-tiles of a given s-split y run on ONE XCD ->
// each 2.56MB split streams from HBM once per XCD, L2-hits for the rest.
// Per chunk: 32 s-rows staged (32KB, dbuf), wave does 32 MFMA into one f32x16.
// C layout (m74/m101): col=lane&31=q, row=(reg&3)+8*(reg>>2)+4*(lane>>5).
__global__ __launch_bounds__(256, 2) void sim_topk(const unsigned short* __restrict__ qn,
                                                   const unsigned short* __restrict__ sn,
                                                   float* __restrict__ partial) {
    __shared__ unsigned short Bs[2][SC * CDIM];   // 2 x 32KB, XOR-swizzled rows
    int id = blockIdx.x;
    int xcd = id & 7, j = id >> 3;
    int y = xcd * 2 + (j & 1);        // s-split, pinned to XCD
    int x = j >> 1;                   // q-tile 0..31
    int tid = threadIdx.x, lane = tid & 63, wid = tid >> 6;
    int rlo = lane & 31;
    int qbase = x * QT + wid * 32;
    int sbase = y * SPER;
    char* BsB = (char*)&Bs[0][0];
    const char* snB = (const char*)sn;

    // B fragments (q side): 32 q rows, full K=512. k = ks*16 + (lane>>5)*8 + e.
    u32x4 b[32];
    {
        const unsigned short* qp = qn + (size_t)(qbase + rlo) * CDIM + ((lane >> 5) * 8);
#pragma unroll
        for (int ks = 0; ks < 32; ++ks) b[ks] = *(const u32x4*)(qp + ks * 16);
    }

    float r[15];
#pragma unroll
    for (int i = 0; i < 15; ++i) r[i] = -2.0f;   // below min cosine

    auto stage = [&](int ch, int buf) {
#pragma unroll
        for (int i = 0; i < 8; ++i) {
            int row = i * 4 + wid;                       // wave-uniform, 0..31
            size_t srcoff = ((size_t)(sbase + ch * SC + row) << 10)
                          + (size_t)((lane * 16) ^ ((row & 7) << 4));
            async_load16(snB + srcoff, BsB + buf * 32768 + row * 1024);
        }
    };

    int swz = (rlo & 7) << 4;
    int rowbase = rlo * 1024;
    int innerbase = (lane >> 5) * 16;

    stage(0, 0);
    stage(1, 1);
    for (int it = 0; it < NCHUNK / 2; ++it) {
        int ch = 2 * it;
        // ---- even chunk (buf0) ----
        asm volatile("s_waitcnt vmcnt(8)" ::: "memory");   // chunk ch's loads landed
        __builtin_amdgcn_s_barrier();
        f32x16 acc;
#pragma unroll
        for (int e = 0; e < 16; ++e) acc[e] = 0.f;
        __builtin_amdgcn_s_setprio(1);
#pragma unroll
        for (int ks = 0; ks < 32; ++ks) {
            int inner = (ks * 32 + innerbase) ^ swz;
            bf16x8 a = __builtin_bit_cast(bf16x8, *(const u32x4*)(BsB + rowbase + inner));
            acc = __builtin_amdgcn_mfma_f32_32x32x16_bf16(a, __builtin_bit_cast(bf16x8, b[ks]), acc, 0, 0, 0);
        }
        __builtin_amdgcn_s_setprio(0);
        __builtin_amdgcn_s_barrier();   // all reads of buf0 retired
        { int n = ch + 2; if (n >= NCHUNK) n -= NCHUNK; stage(n, 0); }
#pragma unroll
        for (int e = 0; e < 16; ++e) {
            float v = acc[e];
            if (__any(v > r[14])) ins15(r, v);   // wave-uniform skip; ins15 exact
        }

        // ---- odd chunk (buf1) ----
        asm volatile("s_waitcnt vmcnt(8)" ::: "memory");
        __builtin_amdgcn_s_barrier();
        f32x16 acc2;
#pragma unroll
        for (int e = 0; e < 16; ++e) acc2[e] = 0.f;
        __builtin_amdgcn_s_setprio(1);
#pragma unroll
        for (int ks = 0; ks < 32; ++ks) {
            int inner = (ks * 32 + innerbase) ^ swz;
            bf16x8 a = __builtin_bit_cast(bf16x8, *(const u32x4*)(BsB + 32768 + rowbase + inner));
            acc2 = __builtin_amdgcn_mfma_f32_32x32x16_bf16(a, __builtin_bit_cast(bf16x8, b[ks]), acc2, 0, 0, 0);
        }
        __builtin_amdgcn_s_setprio(0);
        __builtin_amdgcn_s_barrier();
        { int n = ch + 3; if (n >= NCHUNK) n -= NCHUNK; stage(n, 1); }
#pragma unroll
        for (int e = 0; e < 16; ++e) {
            float v = acc2[e];
            if (__any(v > r[14])) ins15(r, v);
        }
    }

    // Emit: partial[qrow][split][sub][15], sub = lane>>5
    int qrow = qbase + rlo;
    float* dst = partial + (((size_t)qrow * NSPLIT + y) * 2 + (lane >> 5)) * 15;
#pragma unroll
    for (int i = 0; i < 15; ++i) dst[i] = r[i];
}

// ---------------- Final: merge 480 candidates/row -> top15 -> LSE/top4 loss ----------------
__global__ __launch_bounds__(64) void topk_loss(const float* __restrict__ partial,
                                                float* __restrict__ accum) {
    int r = blockIdx.x, t = threadIdx.x;
    __shared__ float sc[512];
    __shared__ float top[15];
#pragma unroll
    for (int i = 0; i < 8; ++i) {
        int idx = t + 64 * i;
        sc[idx] = (idx < NCAND) ? partial[(size_t)r * NCAND + idx] : -1e30f;
    }
    __syncthreads();
    for (int round = 0; round < 15; ++round) {
        float m = -1e30f;
        int mi = 0;
#pragma unroll
        for (int i = 0; i < 8; ++i) {
            float v = sc[t + 64 * i];
            if (v > m) { m = v; mi = t + 64 * i; }
        }
#pragma unroll
        for (int o = 32; o > 0; o >>= 1) {
            float om = __shfl_down(m, o, 64);
            int oi = __shfl_down(mi, o, 64);
            if (om > m) { m = om; mi = oi; }
        }
        if (t == 0) { top[round] = m; sc[mi] = -1e30f; }
        __syncthreads();
    }
    if (t == 0) {
        float m = top[0], s = 0.f;
#pragma unroll
        for (int i = 0; i < 15; ++i) s += expf(top[i] - m);
        float lse = m + logf(s);
        float loss = lse - 0.25f * (top[0] + top[1] + top[2] + top[3]);
        atomicAdd(accum, loss);
    }
}

__global__ void finalize_out(const float* __restrict__ accum, float* __restrict__ out) {
    out[0] = accum[0] * (1.0f / (float)NQ);
}

// ---------------- Launch ----------------
extern "C" void kernel_launch(void* const* d_in, const int* in_sizes, int n_in,
                              void* d_out, int out_size, void* d_ws, size_t ws_size,
                              hipStream_t stream) {
    (void)in_sizes; (void)n_in; (void)out_size; (void)ws_size;
    const float* q = (const float*)d_in[0];
    const float* S = (const float*)d_in[1];
    char* ws = (char*)d_ws;
    unsigned short* qn = (unsigned short*)ws;                        // 4,194,304 B
    unsigned short* sn = (unsigned short*)(ws + 4194304);            // 41,943,040 B
    float* partial = (float*)(ws + 4194304 + 41943040);              // 7,864,320 B
    float* accum   = (float*)(ws + 4194304 + 41943040 + 7864320);    // 4 B

    hipMemsetAsync(accum, 0, 4, stream);
    pool_q_norm<<<512, 256, 0, stream>>>(q, qn);
    pool_s_norm<<<1024, 256, 0, stream>>>(S, sn);
    sim_topk<<<512, 256, 0, stream>>>(qn, sn, partial);
    topk_loss<<<NQ, 64, 0, stream>>>(partial, accum);
    finalize_out<<<1, 1, 0, stream>>>(accum, (float*)d_out);
}